// Round 13
// baseline (1223.655 us; speedup 1.0000x reference)
//
#include <hip/hip_runtime.h>
#include <hip/hip_bf16.h>

// Problem constants
#define B_   32
#define L_   512
#define D_   512
#define H_   8
#define NL_  6
#define F_   2048
#define C_   9
#define HD_  64
#define MTOK 16384   // B_*L_

typedef __bf16 bf16x8 __attribute__((ext_vector_type(8)));
typedef __bf16 bf16x4 __attribute__((ext_vector_type(4)));
typedef float  f32x4  __attribute__((ext_vector_type(4)));

#define MFMA16(a,b,c) __builtin_amdgcn_mfma_f32_16x16x32_bf16((a),(b),(c),0,0,0)
#define GLD16(g,l) __builtin_amdgcn_global_load_lds( \
    (const __attribute__((address_space(1))) void*)(g), \
    (__attribute__((address_space(3))) void*)(l), 16, 0, 0)

// ---------------------------------------------------------------------------
// Weight transpose + f32->bf16: in [z][K][N] f32 -> out [z-stride zso][N][K]
// ---------------------------------------------------------------------------
__global__ __launch_bounds__(256) void transpose_w(
    const float* __restrict__ in, __hip_bfloat16* __restrict__ out,
    int K, int N, size_t zso)
{
    __shared__ float t[32][33];
    const int z = blockIdx.z;
    const float* src = in + (size_t)z * K * N;
    __hip_bfloat16* dst = out + (size_t)z * zso;
    const int n0 = blockIdx.x * 32, k0 = blockIdx.y * 32;
    const int tx = threadIdx.x, ty = threadIdx.y;   // (32,8)
#pragma unroll
    for (int r = ty; r < 32; r += 8)
        t[r][tx] = src[(size_t)(k0 + r) * N + n0 + tx];
    __syncthreads();
#pragma unroll
    for (int r = ty; r < 32; r += 8)
        dst[(size_t)(n0 + r) * K + k0 + tx] = __float2bfloat16(t[tx][r]);
}

// ---------------------------------------------------------------------------
// f32 -> bf16 convert (x -> bf16 residual stream), 8 elems/thread
// ---------------------------------------------------------------------------
__global__ void cvt_f32_bf16(const float4* __restrict__ in,
                             __hip_bfloat16* __restrict__ out, int n8)
{
    int i = blockIdx.x * blockDim.x + threadIdx.x;
    if (i >= n8) return;
    float4 a = in[2 * i], b = in[2 * i + 1];
    bf16x8 o;
    o[0] = (__bf16)a.x; o[1] = (__bf16)a.y; o[2] = (__bf16)a.z; o[3] = (__bf16)a.w;
    o[4] = (__bf16)b.x; o[5] = (__bf16)b.y; o[6] = (__bf16)b.z; o[7] = (__bf16)b.w;
    *(bf16x8*)(out + (size_t)i * 8) = o;
}

// ---------------------------------------------------------------------------
// bias_build: tab[((l*B+b)*H+h)*9+ci][kv] = cbias[l][h][ci][cj(kv)]
//             + (cj==8)*verb[l][h] - 10000*(1-amask[b][kv])   (bf16)
// ---------------------------------------------------------------------------
__global__ __launch_bounds__(256) void bias_build(
    const int* __restrict__ case_ids, const int* __restrict__ amask,
    const float* __restrict__ cbias, const float* __restrict__ vbias,
    __hip_bfloat16* __restrict__ tab)
{
    const unsigned idx = blockIdx.x * 256 + threadIdx.x;   // < NL*B*H*9*512
    const int kv = idx & 511;
    unsigned r = idx >> 9;
    const int ci = r % 9; r /= 9;
    const int hh = r % H_; r /= H_;
    const int b = r % B_; const int l = r / B_;
    const int cj = case_ids[b * L_ + kv];
    const float v = cbias[(((size_t)l * H_ + hh) * C_ + ci) * C_ + cj]
                  + (cj == 8 ? vbias[l * H_ + hh] : 0.f)
                  - 10000.f * (1.f - (float)amask[b * L_ + kv]);
    tab[idx] = __float2bfloat16(v);
}

// ---------------------------------------------------------------------------
// LayerNorm over bf16 residual stream: one wave per row (D=512 -> 8/lane).
// OUT = bf16 (hbuf) or f32 (final output).
// ---------------------------------------------------------------------------
template <typename OUT>
__global__ __launch_bounds__(256) void ln_kernel(
    const __hip_bfloat16* __restrict__ x, const float* __restrict__ g,
    const float* __restrict__ be, OUT* __restrict__ out)
{
    const int row  = blockIdx.x * 4 + (threadIdx.x >> 6);
    const int lane = threadIdx.x & 63;
    const int c0   = lane * 8;
    const bf16x8 xv = *(const bf16x8*)(x + (size_t)row * D_ + c0);
    float v[8];
#pragma unroll
    for (int j = 0; j < 8; ++j) v[j] = (float)xv[j];

    float s = 0.f;
#pragma unroll
    for (int j = 0; j < 8; ++j) s += v[j];
#pragma unroll
    for (int o = 1; o < 64; o <<= 1) s += __shfl_xor(s, o, 64);
    const float mu = s * (1.0f / D_);

    float s2 = 0.f;
#pragma unroll
    for (int j = 0; j < 8; ++j) { float d = v[j] - mu; s2 += d * d; }
#pragma unroll
    for (int o = 1; o < 64; o <<= 1) s2 += __shfl_xor(s2, o, 64);
    const float rs = rsqrtf(s2 * (1.0f / D_) + 1e-5f);

    float4 g0 = *(const float4*)(g + c0);
    float4 g1 = *(const float4*)(g + c0 + 4);
    float4 b0 = *(const float4*)(be + c0);
    float4 b1 = *(const float4*)(be + c0 + 4);
    float gg[8] = {g0.x, g0.y, g0.z, g0.w, g1.x, g1.y, g1.z, g1.w};
    float bb[8] = {b0.x, b0.y, b0.z, b0.w, b1.x, b1.y, b1.z, b1.w};

    if constexpr (sizeof(OUT) == 2) {
        bf16x8 o8;
#pragma unroll
        for (int j = 0; j < 8; ++j)
            o8[j] = (__bf16)((v[j] - mu) * rs * gg[j] + bb[j]);
        *(bf16x8*)((__hip_bfloat16*)out + (size_t)row * D_ + c0) = o8;
    } else {
        float* op = (float*)out + (size_t)row * D_ + c0;
        float4 r0, r1;
        r0.x = (v[0]-mu)*rs*gg[0]+bb[0]; r0.y = (v[1]-mu)*rs*gg[1]+bb[1];
        r0.z = (v[2]-mu)*rs*gg[2]+bb[2]; r0.w = (v[3]-mu)*rs*gg[3]+bb[3];
        r1.x = (v[4]-mu)*rs*gg[4]+bb[4]; r1.y = (v[5]-mu)*rs*gg[5]+bb[5];
        r1.z = (v[6]-mu)*rs*gg[6]+bb[6]; r1.w = (v[7]-mu)*rs*gg[7]+bb[7];
        *(float4*)op = r0; *(float4*)(op + 4) = r1;
    }
}

// fast branchless tanh-form GELU (max abs err ~2.5e-4 vs exact erf form)
__device__ __forceinline__ float gelu_tanh(float v)
{
    const float t2 = v * v;
    const float u  = v * (0.7978845608028654f + 0.0356774081363001f * t2);
    const float a  = __builtin_fabsf(u);
    const float e  = __expf(-2.0f * a);
    const float r  = __builtin_amdgcn_rcpf(1.0f + e);
    const float th = (1.0f - e) * r;               // |tanh(u)|
    return 0.5f * v + 0.5f * __builtin_fabsf(v) * th;
}

// ---------------------------------------------------------------------------
// gemm_r5: multi-block-overlap GEMM (R7/R10-proven). BK=32, ring-3 LDS,
// counted vmcnt, one s_barrier per K-tile, setprio on MFMA. Per-wave 64x64.
//   WM=4: BM=256 BN=128, 8 waves, LDS 72 KiB, 2 blocks/CU (16 waves/CU) [W1]
//   WM=2: BM=128 BN=128, 4 waves, LDS 48 KiB, 3 blocks/CU (12 waves/CU)
//         [QKV, O, W2]
// EPI: 1 = bf16 residual add (out0==Res, bf16); 2 = tanh-GELU -> bf16;
//      4 = fused QKV epilogue (out0=q, out1=k, out2=VT[b][d][l]).
// ---------------------------------------------------------------------------
template <int EPI, int WM>
__global__ __launch_bounds__(WM * 128, (WM == 4) ? 4 : 3) void gemm_r5(
    const __hip_bfloat16* __restrict__ A,
    const __hip_bfloat16* __restrict__ BT,
    const float* __restrict__ bias0, const float* __restrict__ bias1,
    const float* __restrict__ bias2,
    void* __restrict__ out0, void* __restrict__ out1, void* __restrict__ out2,
    const __hip_bfloat16* __restrict__ Res, int Ndim, int K)
{
    constexpr int THREADS = WM * 128;
    constexpr int BM = WM * 64;
    __shared__ __align__(16) __hip_bfloat16 As[3][BM * 32];
    __shared__ __align__(16) __hip_bfloat16 Bs[3][128 * 32];

    const int tid = threadIdx.x;
    const int w = tid >> 6, lane = tid & 63;
    const int lq = lane & 15, lg = lane >> 4;
    const int wm = w >> 1, wn = w & 1;
    const int RB = wm * 64, CB = wn * 64;

    const int gX = gridDim.x;
    const int nwg = gX * gridDim.y;
    int flat = blockIdx.y * gX + blockIdx.x;
    {
        const int qq = nwg >> 3, rr = nwg & 7;
        const int xcd = flat & 7, off = flat >> 3;
        flat = (xcd < rr ? xcd * (qq + 1) : rr * (qq + 1) + (xcd - rr) * qq) + off;
    }
    const int bx = flat % gX, by = flat / gX;
    const int m0 = by * BM, n0 = bx * 128;

    const int rc = tid >> 2;
    const int sc = ((tid & 3) ^ ((rc >> 1) & 3)) * 8;
    const __hip_bfloat16* gA0 = A  + (size_t)(m0 + rc) * K + sc;
    const __hip_bfloat16* gB0 = BT + (size_t)(n0 + rc) * K + sc;

    auto STAGE = [&](int tt) {
        const size_t ko = (size_t)tt * 32;
        const int sl = tt % 3;
        char* ab = (char*)As[sl] + w * 1024;
        GLD16(gA0 + ko, ab);
        GLD16(gA0 + (size_t)(THREADS / 4) * K + ko, ab + THREADS * 16);
        char* bb = (char*)Bs[sl] + w * 1024;
        GLD16(gB0 + ko, bb);
        if constexpr (WM == 2)
            GLD16(gB0 + (size_t)64 * K + ko, bb + 4096);
    };

    const int rsw = (lq >> 1) & 3;
    const int aoff = (RB + lq) * 64 + ((lg ^ rsw) << 4);
    const int boff = (CB + lq) * 64 + ((lg ^ rsw) << 4);

    f32x4 acc[4][4] = {};
    const int NTt = K >> 5;

    STAGE(0); STAGE(1);

    for (int t = 0; t < NTt; ++t) {
        if (t + 1 < NTt) {
            if constexpr (WM == 4) asm volatile("s_waitcnt vmcnt(3)" ::: "memory");
            else                   asm volatile("s_waitcnt vmcnt(4)" ::: "memory");
        } else {
            asm volatile("s_waitcnt vmcnt(0)" ::: "memory");
        }
        __builtin_amdgcn_s_barrier();
        __builtin_amdgcn_sched_barrier(0);

        const char* ca = (const char*)As[t % 3];
        const char* cb = (const char*)Bs[t % 3];
        bf16x8 af[4], bf[4];
#pragma unroll
        for (int fm = 0; fm < 4; ++fm) af[fm] = *(const bf16x8*)(ca + aoff + fm * 1024);
#pragma unroll
        for (int fn = 0; fn < 4; ++fn) bf[fn] = *(const bf16x8*)(cb + boff + fn * 1024);

        if (t + 2 < NTt) STAGE(t + 2);

        __builtin_amdgcn_s_setprio(1);
#pragma unroll
        for (int fm = 0; fm < 4; ++fm)
#pragma unroll
            for (int fn = 0; fn < 4; ++fn)
                acc[fm][fn] = MFMA16(af[fm], bf[fn], acc[fm][fn]);
        __builtin_amdgcn_s_setprio(0);
    }

    if constexpr (EPI == 4) {
        const int sec = n0 >> 9;
        const int nb = (n0 & 511) + CB;
        const float* bp = sec == 0 ? bias0 : (sec == 1 ? bias1 : bias2);
        float bcol[4];
#pragma unroll
        for (int fn = 0; fn < 4; ++fn) bcol[fn] = bp[nb + fn * 16 + lq];
        if (sec < 2) {
            __hip_bfloat16* op = (__hip_bfloat16*)(sec == 0 ? out0 : out1);
#pragma unroll
            for (int fm = 0; fm < 4; ++fm)
#pragma unroll
                for (int fn = 0; fn < 4; ++fn)
#pragma unroll
                    for (int r = 0; r < 4; ++r) {
                        const int m = m0 + RB + fm * 16 + lg * 4 + r;
                        op[(size_t)m * 512 + nb + fn * 16 + lq] =
                            __float2bfloat16(acc[fm][fn][r] + bcol[fn]);
                    }
        } else {
            __hip_bfloat16* vp = (__hip_bfloat16*)out2;
            const int bb = m0 >> 9;
            const int l0 = (m0 & 511) + RB + lg * 4;
#pragma unroll
            for (int fm = 0; fm < 4; ++fm)
#pragma unroll
                for (int fn = 0; fn < 4; ++fn) {
                    bf16x4 pv;
#pragma unroll
                    for (int r = 0; r < 4; ++r)
                        pv[r] = (__bf16)(acc[fm][fn][r] + bcol[fn]);
                    *(bf16x4*)(vp + ((size_t)(bb * 512 + nb + fn * 16 + lq)) * 512
                               + l0 + fm * 16) = pv;
                }
        }
    } else {
        float bcol[4];
#pragma unroll
        for (int fn = 0; fn < 4; ++fn) bcol[fn] = bias0[n0 + CB + fn * 16 + lq];
#pragma unroll
        for (int fm = 0; fm < 4; ++fm)
#pragma unroll
            for (int fn = 0; fn < 4; ++fn) {
                const int n = n0 + CB + fn * 16 + lq;
#pragma unroll
                for (int r = 0; r < 4; ++r) {
                    const int m = m0 + RB + fm * 16 + lg * 4 + r;
                    float v = acc[fm][fn][r] + bcol[fn];
                    if constexpr (EPI == 1) {
                        __hip_bfloat16* Co = (__hip_bfloat16*)out0;
                        const size_t idx = (size_t)m * Ndim + n;
                        Co[idx] = __float2bfloat16((float)Res[idx] + v);
                    } else {  // EPI == 2: tanh-GELU
                        ((__hip_bfloat16*)out0)[(size_t)m * Ndim + n] =
                            __float2bfloat16(gelu_tanh(v));
                    }
                }
            }
    }
}

// ---------------------------------------------------------------------------
// Flash attention, paired q-chunks (qcA, 7-qcA share staged K/V tiles).
// 1024 1-D blocks with bijective XCD-chunk swizzle so the 4 blocks sharing
// one (b,h)'s K/V land on the SAME XCD L2 (T1 applied to attn). 40 KiB LDS
// -> 4 blocks/CU. T13 defer-max on the O-rescale.
// ---------------------------------------------------------------------------
__global__ __launch_bounds__(256, 4) void attn_kernel(
    const __hip_bfloat16* __restrict__ Q, const __hip_bfloat16* __restrict__ K,
    const __hip_bfloat16* __restrict__ VT, __hip_bfloat16* __restrict__ Out,
    const int* __restrict__ case_ids, const __hip_bfloat16* __restrict__ tab,
    int layer)
{
    __shared__ __align__(16) __bf16 Ks[2][64 * 64];
    __shared__ __align__(16) __bf16 Vs[2][64 * 64];
    __shared__ __align__(16) __bf16 Pl[4][16 * 64];

    // XCD-chunk swizzle: 1024 blocks, 8 XCDs -> XCD x owns tiles
    // [x*128, (x+1)*128) = 32 complete (b,h) groups (4 q-chunks each).
    const int tile = (blockIdx.x & 7) * 128 + (blockIdx.x >> 3);
    const int bh = tile >> 2;
    const int qcA = tile & 3;
    const int b = bh >> 3, hh = bh & 7;
    const int qcB = 7 - qcA;
    const int t = threadIdx.x;
    const int w = t >> 6, lane = t & 63;
    const int lq = lane & 15, lg = lane >> 4;
    const int swz = lq & 7;

    const int rA = w * 16 + (lane >> 3);
    const int swsrc = ((lane & 7) ^ (lane >> 3)) << 4;
    const __hip_bfloat16* kg0 = K  + ((size_t)b * L_ + rA) * D_ + hh * HD_;
    const __hip_bfloat16* vg0 = VT + ((size_t)b * D_ + hh * HD_ + rA) * L_;

    auto stage = [&](int buf, int kv0) {
        const char* gk = (const char*)(kg0 + (size_t)kv0 * D_) + swsrc;
        GLD16(gk,                      (char*)Ks[buf] + w * 2048);
        GLD16(gk + (size_t)8 * D_ * 2, (char*)Ks[buf] + w * 2048 + 1024);
        const char* gv = (const char*)(vg0 + kv0) + swsrc;
        GLD16(gv,                      (char*)Vs[buf] + w * 2048);
        GLD16(gv + (size_t)8 * L_ * 2, (char*)Vs[buf] + w * 2048 + 1024);
    };

    stage(0, 0);

    const int qloc = w * 16 + lq;
    const int qrowA = qcA * 64 + qloc;
    const int qrowB = qcB * 64 + qloc;
    const size_t tbase = (((size_t)layer * B_ + b) * H_ + hh) * C_;
    const __hip_bfloat16* ciqA = tab + (tbase + case_ids[b * L_ + qrowA]) * L_;
    const __hip_bfloat16* ciqB = tab + (tbase + case_ids[b * L_ + qrowB]) * L_;

    const __hip_bfloat16* qpA = Q + ((size_t)b * L_ + qrowA) * D_ + hh * HD_;
    const __hip_bfloat16* qpB = Q + ((size_t)b * L_ + qrowB) * D_ + hh * HD_;
    const bf16x8 qfA0 = *(const bf16x8*)(qpA + lg * 8);
    const bf16x8 qfA1 = *(const bf16x8*)(qpA + 32 + lg * 8);
    const bf16x8 qfB0 = *(const bf16x8*)(qpB + lg * 8);
    const bf16x8 qfB1 = *(const bf16x8*)(qpB + 32 + lg * 8);

    float mA = -1e30f, lA = 0.f, mB = -1e30f, lB = 0.f;
    f32x4 oA[4] = {}, oB[4] = {};
    int cur = 0;

    auto process = [&](const bf16x8 qf0, const bf16x8 qf1,
                       const __hip_bfloat16* ciq, int qcX,
                       float& m_run, float& l_run, f32x4* o,
                       const char* kb, const char* vb2, int kt) {
        bf16x4 bb[4];
#pragma unroll
        for (int c = 0; c < 4; ++c)
            bb[c] = *(const bf16x4*)(ciq + kt * 64 + 16 * c + lg * 4);

        f32x4 s[4] = {};
        __builtin_amdgcn_s_setprio(1);
#pragma unroll
        for (int c = 0; c < 4; ++c) {
            const bf16x8 ka = *(const bf16x8*)(kb + (16 * c + lq) * 128 + ((lg ^ swz) << 4));
            s[c] = MFMA16(ka, qf0, s[c]);
            const bf16x8 kc = *(const bf16x8*)(kb + (16 * c + lq) * 128 + (((4 + lg) ^ swz) << 4));
            s[c] = MFMA16(kc, qf1, s[c]);
        }
        __builtin_amdgcn_s_setprio(0);

        const bool dtile = (kt == qcX);
        float xs[16];
#pragma unroll
        for (int c = 0; c < 4; ++c)
#pragma unroll
            for (int r = 0; r < 4; ++r) {
                const int kvl = 16 * c + lg * 4 + r;
                float v = s[c][r] * 0.125f + (float)bb[c][r];
                xs[4 * c + r] = (dtile && (kvl > qloc)) ? -1e9f : v;
            }

        float a0 = fmaxf(fmaxf(xs[0], xs[1]),  fmaxf(xs[2], xs[3]));
        float a1 = fmaxf(fmaxf(xs[4], xs[5]),  fmaxf(xs[6], xs[7]));
        float a2 = fmaxf(fmaxf(xs[8], xs[9]),  fmaxf(xs[10], xs[11]));
        float a3 = fmaxf(fmaxf(xs[12], xs[13]), fmaxf(xs[14], xs[15]));
        float pmax = fmaxf(fmaxf(a0, a1), fmaxf(a2, a3));
        pmax = fmaxf(pmax, __shfl_xor(pmax, 16, 64));
        pmax = fmaxf(pmax, __shfl_xor(pmax, 32, 64));

        // T13 defer-max: rescale only if some q-row's max grew by > 8.
        if (!__all(pmax - m_run <= 8.f)) {
            const float mnew = fmaxf(m_run, pmax);
            const float corr = __expf(m_run - mnew);
            m_run = mnew;
            l_run *= corr;
            float cr[4];
#pragma unroll
            for (int r = 0; r < 4; ++r) cr[r] = __shfl(corr, lg * 4 + r, 64);
#pragma unroll
            for (int nt = 0; nt < 4; ++nt)
#pragma unroll
                for (int r = 0; r < 4; ++r) o[nt][r] *= cr[r];
        }

        float ps = 0.f;
#pragma unroll
        for (int j = 0; j < 16; ++j) { xs[j] = __expf(xs[j] - m_run); ps += xs[j]; }
        ps += __shfl_xor(ps, 16, 64);
        ps += __shfl_xor(ps, 32, 64);
        l_run += ps;

        char* pw = (char*)Pl[w];
#pragma unroll
        for (int c = 0; c < 4; ++c) {
            bf16x4 pv;
#pragma unroll
            for (int r = 0; r < 4; ++r) pv[r] = (__bf16)xs[4 * c + r];
            const int slot = (2 * c + (lg >> 1)) ^ swz;
            *(bf16x4*)(pw + lq * 128 + (slot << 4) + ((lg & 1) << 3)) = pv;
        }

        __builtin_amdgcn_s_setprio(1);
#pragma unroll
        for (int hf = 0; hf < 2; ++hf) {
            const bf16x8 pf = *(const bf16x8*)(pw + lq * 128 + (((hf * 4 + lg) ^ swz) << 4));
#pragma unroll
            for (int nt = 0; nt < 4; ++nt) {
                const bf16x8 vf = *(const bf16x8*)(vb2 + (nt * 16 + lq) * 128
                                                   + (((hf * 4 + lg) ^ swz) << 4));
                o[nt] = MFMA16(pf, vf, o[nt]);
            }
        }
        __builtin_amdgcn_s_setprio(0);
    };

    for (int kt = 0; kt <= qcB; ++kt) {
        if (kt) __builtin_amdgcn_s_barrier();
        if (kt < qcB) {
            stage(cur ^ 1, (kt + 1) * 64);
            asm volatile("s_waitcnt vmcnt(4)" ::: "memory");
        } else {
            asm volatile("s_waitcnt vmcnt(0)" ::: "memory");
        }
        __builtin_amdgcn_s_barrier();
        __builtin_amdgcn_sched_barrier(0);

        const char* kb  = (const char*)Ks[cur];
        const char* vb2 = (const char*)Vs[cur];

        process(qfB0, qfB1, ciqB, qcB, mB, lB, oB, kb, vb2, kt);
        if (kt <= qcA)
            process(qfA0, qfA1, ciqA, qcA, mA, lA, oA, kb, vb2, kt);
        cur ^= 1;
    }

    auto writeout = [&](float l_run, f32x4* o, int qcX) {
        const float inv = 1.f / l_run;
        float ir[4];
#pragma unroll
        for (int r = 0; r < 4; ++r) ir[r] = __shfl(inv, lg * 4 + r, 64);
        __hip_bfloat16* op = Out + ((size_t)b * L_ + qcX * 64 + w * 16) * D_ + hh * HD_;
#pragma unroll
        for (int nt = 0; nt < 4; ++nt)
#pragma unroll
            for (int r = 0; r < 4; ++r)
                op[(size_t)(lg * 4 + r) * D_ + nt * 16 + lq] =
                    __float2bfloat16(o[nt][r] * ir[r]);
    };
    writeout(lA, oA, qcA);
    writeout(lB, oB, qcB);
}

// ---------------------------------------------------------------------------
extern "C" void kernel_launch(void* const* d_in, const int* in_sizes, int n_in,
                              void* d_out, int out_size, void* d_ws, size_t ws_size,
                              hipStream_t stream)
{
    const float* x_in  = (const float*)d_in[0];
    const int*   cids  = (const int*)  d_in[1];
    const int*   amask = (const int*)  d_in[2];
    const float* Wq = (const float*)d_in[3];
    const float* bq = (const float*)d_in[4];
    const float* Wk = (const float*)d_in[5];
    const float* bk = (const float*)d_in[6];
    const float* Wv = (const float*)d_in[7];
    const float* bv = (const float*)d_in[8];
    const float* Wo = (const float*)d_in[9];
    const float* bo = (const float*)d_in[10];
    const float* ln1g = (const float*)d_in[11];
    const float* ln1b = (const float*)d_in[12];
    const float* ln2g = (const float*)d_in[13];
    const float* ln2b = (const float*)d_in[14];
    const float* W1 = (const float*)d_in[15];
    const float* b1 = (const float*)d_in[16];
    const float* W2 = (const float*)d_in[17];
    const float* b2 = (const float*)d_in[18];
    const float* cbias = (const float*)d_in[19];
    const float* vbias = (const float*)d_in[20];
    const float* fng = (const float*)d_in[21];
    const float* fnb = (const float*)d_in[22];

    char* w = (char*)d_ws;
    __hip_bfloat16* x_ws = (__hip_bfloat16*)w;  w += (size_t)MTOK * D_ * 2;
    __hip_bfloat16* hbuf = (__hip_bfloat16*)w;  w += (size_t)MTOK * D_ * 2;
    __hip_bfloat16* qbuf = (__hip_bfloat16*)w;  w += (size_t)MTOK * D_ * 2;
    __hip_bfloat16* kbuf = (__hip_bfloat16*)w;  w += (size_t)MTOK * D_ * 2;
    __hip_bfloat16* vtb  = (__hip_bfloat16*)w;  w += (size_t)MTOK * D_ * 2;
    __hip_bfloat16* ffb  = (__hip_bfloat16*)w;  w += (size_t)MTOK * F_ * 2;
    __hip_bfloat16* WqkvT = (__hip_bfloat16*)w; w += (size_t)NL_ * 3 * D_ * D_ * 2;
    __hip_bfloat16* WoT  = (__hip_bfloat16*)w;  w += (size_t)NL_ * D_ * D_ * 2;
    __hip_bfloat16* W1T  = (__hip_bfloat16*)w;  w += (size_t)NL_ * D_ * F_ * 2;
    __hip_bfloat16* W2T  = (__hip_bfloat16*)w;  w += (size_t)NL_ * D_ * F_ * 2;
    __hip_bfloat16* btab = (__hip_bfloat16*)w;  w += (size_t)NL_ * B_ * H_ * C_ * L_ * 2;

    const size_t qkvZ = (size_t)3 * D_ * D_;
    const dim3 tb(32, 8);
    transpose_w<<<dim3(D_/32, D_/32, NL_), tb, 0, stream>>>(Wq, WqkvT,           D_, D_, qkvZ);
    transpose_w<<<dim3(D_/32, D_/32, NL_), tb, 0, stream>>>(Wk, WqkvT + D_*D_,   D_, D_, qkvZ);
    transpose_w<<<dim3(D_/32, D_/32, NL_), tb, 0, stream>>>(Wv, WqkvT + 2*D_*D_, D_, D_, qkvZ);
    transpose_w<<<dim3(D_/32, D_/32, NL_), tb, 0, stream>>>(Wo, WoT, D_, D_, (size_t)D_*D_);
    transpose_w<<<dim3(F_/32, D_/32, NL_), tb, 0, stream>>>(W1, W1T, D_, F_, (size_t)D_*F_);
    transpose_w<<<dim3(D_/32, F_/32, NL_), tb, 0, stream>>>(W2, W2T, F_, D_, (size_t)D_*F_);

    bias_build<<<(NL_ * B_ * H_ * C_ * L_) / 256, 256, 0, stream>>>(
        cids, amask, cbias, vbias, btab);

    cvt_f32_bf16<<<4096, 256, 0, stream>>>((const float4*)x_in, x_ws,
                                           MTOK * D_ / 8);

    const dim3 gQKV(12, 128);  // WM=2: 1536 blocks = 2 rounds at 3/CU
    const dim3 gO(4, 128);     // 512 blocks
    const dim3 gW1(16, 64);    // WM=4: 1024 blocks = 2 rounds at 2/CU
    const dim3 gW2(4, 128);    // 512 blocks

    for (int i = 0; i < NL_; ++i) {
        ln_kernel<__hip_bfloat16><<<MTOK/4, 256, 0, stream>>>(
            x_ws, ln1g + i * D_, ln1b + i * D_, hbuf);

        gemm_r5<4, 2><<<gQKV, 256, 0, stream>>>(hbuf, WqkvT + (size_t)i * qkvZ,
            bq + i*D_, bk + i*D_, bv + i*D_, qbuf, kbuf, vtb, nullptr, 512, D_);

        attn_kernel<<<1024, 256, 0, stream>>>(
            qbuf, kbuf, vtb, hbuf, cids, btab, i);

        gemm_r5<1, 2><<<gO, 256, 0, stream>>>(hbuf, WoT + (size_t)i*D_*D_,
            bo + i*D_, nullptr, nullptr, x_ws, nullptr, nullptr, x_ws, D_, D_);

        ln_kernel<__hip_bfloat16><<<MTOK/4, 256, 0, stream>>>(
            x_ws, ln2g + i * D_, ln2b + i * D_, hbuf);

        gemm_r5<2, 4><<<gW1, 512, 0, stream>>>(hbuf, W1T + (size_t)i*D_*F_,
            b1 + i*F_, nullptr, nullptr, ffb, nullptr, nullptr, nullptr, F_, D_);

        gemm_r5<1, 2><<<gW2, 256, 0, stream>>>(ffb, W2T + (size_t)i*D_*F_,
            b2 + i*D_, nullptr, nullptr, x_ws, nullptr, nullptr, x_ws, D_, F_);
    }

    ln_kernel<float><<<MTOK/4, 256, 0, stream>>>(x_ws, fng, fnb, (float*)d_out);
}

// Round 14
// 1208.357 us; speedup vs baseline: 1.0127x; 1.0127x over previous
//
#include <hip/hip_runtime.h>
#include <hip/hip_bf16.h>

// Problem constants
#define B_   32
#define L_   512
#define D_   512
#define H_   8
#define NL_  6
#define F_   2048
#define C_   9
#define HD_  64
#define MTOK 16384   // B_*L_

typedef __bf16 bf16x8 __attribute__((ext_vector_type(8)));
typedef __bf16 bf16x4 __attribute__((ext_vector_type(4)));
typedef float  f32x4  __attribute__((ext_vector_type(4)));

#define MFMA16(a,b,c) __builtin_amdgcn_mfma_f32_16x16x32_bf16((a),(b),(c),0,0,0)
#define GLD16(g,l) __builtin_amdgcn_global_load_lds( \
    (const __attribute__((address_space(1))) void*)(g), \
    (__attribute__((address_space(3))) void*)(l), 16, 0, 0)

// ---------------------------------------------------------------------------
// Weight transpose + f32->bf16: in [z][K][N] f32 -> out [z-stride zso][N][K]
// ---------------------------------------------------------------------------
__global__ __launch_bounds__(256) void transpose_w(
    const float* __restrict__ in, __hip_bfloat16* __restrict__ out,
    int K, int N, size_t zso)
{
    __shared__ float t[32][33];
    const int z = blockIdx.z;
    const float* src = in + (size_t)z * K * N;
    __hip_bfloat16* dst = out + (size_t)z * zso;
    const int n0 = blockIdx.x * 32, k0 = blockIdx.y * 32;
    const int tx = threadIdx.x, ty = threadIdx.y;   // (32,8)
#pragma unroll
    for (int r = ty; r < 32; r += 8)
        t[r][tx] = src[(size_t)(k0 + r) * N + n0 + tx];
    __syncthreads();
#pragma unroll
    for (int r = ty; r < 32; r += 8)
        dst[(size_t)(n0 + r) * K + k0 + tx] = __float2bfloat16(t[tx][r]);
}

// ---------------------------------------------------------------------------
// f32 -> bf16 convert (x -> bf16 residual stream), 8 elems/thread
// ---------------------------------------------------------------------------
__global__ void cvt_f32_bf16(const float4* __restrict__ in,
                             __hip_bfloat16* __restrict__ out, int n8)
{
    int i = blockIdx.x * blockDim.x + threadIdx.x;
    if (i >= n8) return;
    float4 a = in[2 * i], b = in[2 * i + 1];
    bf16x8 o;
    o[0] = (__bf16)a.x; o[1] = (__bf16)a.y; o[2] = (__bf16)a.z; o[3] = (__bf16)a.w;
    o[4] = (__bf16)b.x; o[5] = (__bf16)b.y; o[6] = (__bf16)b.z; o[7] = (__bf16)b.w;
    *(bf16x8*)(out + (size_t)i * 8) = o;
}

// ---------------------------------------------------------------------------
// bias_build: tab[((l*B+b)*H+h)*9+ci][kv] = cbias[l][h][ci][cj(kv)]
//             + (cj==8)*verb[l][h] - 10000*(1-amask[b][kv])   (bf16)
// ---------------------------------------------------------------------------
__global__ __launch_bounds__(256) void bias_build(
    const int* __restrict__ case_ids, const int* __restrict__ amask,
    const float* __restrict__ cbias, const float* __restrict__ vbias,
    __hip_bfloat16* __restrict__ tab)
{
    const unsigned idx = blockIdx.x * 256 + threadIdx.x;   // < NL*B*H*9*512
    const int kv = idx & 511;
    unsigned r = idx >> 9;
    const int ci = r % 9; r /= 9;
    const int hh = r % H_; r /= H_;
    const int b = r % B_; const int l = r / B_;
    const int cj = case_ids[b * L_ + kv];
    const float v = cbias[(((size_t)l * H_ + hh) * C_ + ci) * C_ + cj]
                  + (cj == 8 ? vbias[l * H_ + hh] : 0.f)
                  - 10000.f * (1.f - (float)amask[b * L_ + kv]);
    tab[idx] = __float2bfloat16(v);
}

// ---------------------------------------------------------------------------
// LayerNorm over bf16 residual stream: one wave per row (D=512 -> 8/lane).
// OUT = bf16 (hbuf) or f32 (final output).
// ---------------------------------------------------------------------------
template <typename OUT>
__global__ __launch_bounds__(256) void ln_kernel(
    const __hip_bfloat16* __restrict__ x, const float* __restrict__ g,
    const float* __restrict__ be, OUT* __restrict__ out)
{
    const int row  = blockIdx.x * 4 + (threadIdx.x >> 6);
    const int lane = threadIdx.x & 63;
    const int c0   = lane * 8;
    const bf16x8 xv = *(const bf16x8*)(x + (size_t)row * D_ + c0);
    float v[8];
#pragma unroll
    for (int j = 0; j < 8; ++j) v[j] = (float)xv[j];

    float s = 0.f;
#pragma unroll
    for (int j = 0; j < 8; ++j) s += v[j];
#pragma unroll
    for (int o = 1; o < 64; o <<= 1) s += __shfl_xor(s, o, 64);
    const float mu = s * (1.0f / D_);

    float s2 = 0.f;
#pragma unroll
    for (int j = 0; j < 8; ++j) { float d = v[j] - mu; s2 += d * d; }
#pragma unroll
    for (int o = 1; o < 64; o <<= 1) s2 += __shfl_xor(s2, o, 64);
    const float rs = rsqrtf(s2 * (1.0f / D_) + 1e-5f);

    float4 g0 = *(const float4*)(g + c0);
    float4 g1 = *(const float4*)(g + c0 + 4);
    float4 b0 = *(const float4*)(be + c0);
    float4 b1 = *(const float4*)(be + c0 + 4);
    float gg[8] = {g0.x, g0.y, g0.z, g0.w, g1.x, g1.y, g1.z, g1.w};
    float bb[8] = {b0.x, b0.y, b0.z, b0.w, b1.x, b1.y, b1.z, b1.w};

    if constexpr (sizeof(OUT) == 2) {
        bf16x8 o8;
#pragma unroll
        for (int j = 0; j < 8; ++j)
            o8[j] = (__bf16)((v[j] - mu) * rs * gg[j] + bb[j]);
        *(bf16x8*)((__hip_bfloat16*)out + (size_t)row * D_ + c0) = o8;
    } else {
        float* op = (float*)out + (size_t)row * D_ + c0;
        float4 r0, r1;
        r0.x = (v[0]-mu)*rs*gg[0]+bb[0]; r0.y = (v[1]-mu)*rs*gg[1]+bb[1];
        r0.z = (v[2]-mu)*rs*gg[2]+bb[2]; r0.w = (v[3]-mu)*rs*gg[3]+bb[3];
        r1.x = (v[4]-mu)*rs*gg[4]+bb[4]; r1.y = (v[5]-mu)*rs*gg[5]+bb[5];
        r1.z = (v[6]-mu)*rs*gg[6]+bb[6]; r1.w = (v[7]-mu)*rs*gg[7]+bb[7];
        *(float4*)op = r0; *(float4*)(op + 4) = r1;
    }
}

// fast branchless tanh-form GELU (max abs err ~2.5e-4 vs exact erf form)
__device__ __forceinline__ float gelu_tanh(float v)
{
    const float t2 = v * v;
    const float u  = v * (0.7978845608028654f + 0.0356774081363001f * t2);
    const float a  = __builtin_fabsf(u);
    const float e  = __expf(-2.0f * a);
    const float r  = __builtin_amdgcn_rcpf(1.0f + e);
    const float th = (1.0f - e) * r;               // |tanh(u)|
    return 0.5f * v + 0.5f * __builtin_fabsf(v) * th;
}

// ---------------------------------------------------------------------------
// gemm_r5: multi-block-overlap GEMM (R7/R10-proven). BK=32, ring-3 LDS,
// counted vmcnt, one s_barrier per K-tile, setprio on MFMA. Per-wave 64x64.
//   WM=4: BM=256 BN=128, 8 waves, LDS 72 KiB, 2 blocks/CU (16 waves/CU) [W1]
//   WM=2: BM=128 BN=128, 4 waves, LDS 48 KiB, 3 blocks/CU (12 waves/CU)
//         [QKV, O, W2]
// EPI: 1 = bf16 residual add (out0==Res, bf16); 2 = tanh-GELU -> bf16;
//      4 = fused QKV epilogue (out0=q, out1=k, out2=VT[b][d][l]).
// ---------------------------------------------------------------------------
template <int EPI, int WM>
__global__ __launch_bounds__(WM * 128, (WM == 4) ? 4 : 3) void gemm_r5(
    const __hip_bfloat16* __restrict__ A,
    const __hip_bfloat16* __restrict__ BT,
    const float* __restrict__ bias0, const float* __restrict__ bias1,
    const float* __restrict__ bias2,
    void* __restrict__ out0, void* __restrict__ out1, void* __restrict__ out2,
    const __hip_bfloat16* __restrict__ Res, int Ndim, int K)
{
    constexpr int THREADS = WM * 128;
    constexpr int BM = WM * 64;
    __shared__ __align__(16) __hip_bfloat16 As[3][BM * 32];
    __shared__ __align__(16) __hip_bfloat16 Bs[3][128 * 32];

    const int tid = threadIdx.x;
    const int w = tid >> 6, lane = tid & 63;
    const int lq = lane & 15, lg = lane >> 4;
    const int wm = w >> 1, wn = w & 1;
    const int RB = wm * 64, CB = wn * 64;

    const int gX = gridDim.x;
    const int nwg = gX * gridDim.y;
    int flat = blockIdx.y * gX + blockIdx.x;
    {
        const int qq = nwg >> 3, rr = nwg & 7;
        const int xcd = flat & 7, off = flat >> 3;
        flat = (xcd < rr ? xcd * (qq + 1) : rr * (qq + 1) + (xcd - rr) * qq) + off;
    }
    const int bx = flat % gX, by = flat / gX;
    const int m0 = by * BM, n0 = bx * 128;

    const int rc = tid >> 2;
    const int sc = ((tid & 3) ^ ((rc >> 1) & 3)) * 8;
    const __hip_bfloat16* gA0 = A  + (size_t)(m0 + rc) * K + sc;
    const __hip_bfloat16* gB0 = BT + (size_t)(n0 + rc) * K + sc;

    auto STAGE = [&](int tt) {
        const size_t ko = (size_t)tt * 32;
        const int sl = tt % 3;
        char* ab = (char*)As[sl] + w * 1024;
        GLD16(gA0 + ko, ab);
        GLD16(gA0 + (size_t)(THREADS / 4) * K + ko, ab + THREADS * 16);
        char* bb = (char*)Bs[sl] + w * 1024;
        GLD16(gB0 + ko, bb);
        if constexpr (WM == 2)
            GLD16(gB0 + (size_t)64 * K + ko, bb + 4096);
    };

    const int rsw = (lq >> 1) & 3;
    const int aoff = (RB + lq) * 64 + ((lg ^ rsw) << 4);
    const int boff = (CB + lq) * 64 + ((lg ^ rsw) << 4);

    f32x4 acc[4][4] = {};
    const int NTt = K >> 5;

    STAGE(0); STAGE(1);

    for (int t = 0; t < NTt; ++t) {
        if (t + 1 < NTt) {
            if constexpr (WM == 4) asm volatile("s_waitcnt vmcnt(3)" ::: "memory");
            else                   asm volatile("s_waitcnt vmcnt(4)" ::: "memory");
        } else {
            asm volatile("s_waitcnt vmcnt(0)" ::: "memory");
        }
        __builtin_amdgcn_s_barrier();
        __builtin_amdgcn_sched_barrier(0);

        const char* ca = (const char*)As[t % 3];
        const char* cb = (const char*)Bs[t % 3];
        bf16x8 af[4], bf[4];
#pragma unroll
        for (int fm = 0; fm < 4; ++fm) af[fm] = *(const bf16x8*)(ca + aoff + fm * 1024);
#pragma unroll
        for (int fn = 0; fn < 4; ++fn) bf[fn] = *(const bf16x8*)(cb + boff + fn * 1024);

        if (t + 2 < NTt) STAGE(t + 2);

        __builtin_amdgcn_s_setprio(1);
#pragma unroll
        for (int fm = 0; fm < 4; ++fm)
#pragma unroll
            for (int fn = 0; fn < 4; ++fn)
                acc[fm][fn] = MFMA16(af[fm], bf[fn], acc[fm][fn]);
        __builtin_amdgcn_s_setprio(0);
    }

    if constexpr (EPI == 4) {
        const int sec = n0 >> 9;
        const int nb = (n0 & 511) + CB;
        const float* bp = sec == 0 ? bias0 : (sec == 1 ? bias1 : bias2);
        float bcol[4];
#pragma unroll
        for (int fn = 0; fn < 4; ++fn) bcol[fn] = bp[nb + fn * 16 + lq];
        if (sec < 2) {
            __hip_bfloat16* op = (__hip_bfloat16*)(sec == 0 ? out0 : out1);
#pragma unroll
            for (int fm = 0; fm < 4; ++fm)
#pragma unroll
                for (int fn = 0; fn < 4; ++fn)
#pragma unroll
                    for (int r = 0; r < 4; ++r) {
                        const int m = m0 + RB + fm * 16 + lg * 4 + r;
                        op[(size_t)m * 512 + nb + fn * 16 + lq] =
                            __float2bfloat16(acc[fm][fn][r] + bcol[fn]);
                    }
        } else {
            __hip_bfloat16* vp = (__hip_bfloat16*)out2;
            const int bb = m0 >> 9;
            const int l0 = (m0 & 511) + RB + lg * 4;
#pragma unroll
            for (int fm = 0; fm < 4; ++fm)
#pragma unroll
                for (int fn = 0; fn < 4; ++fn) {
                    bf16x4 pv;
#pragma unroll
                    for (int r = 0; r < 4; ++r)
                        pv[r] = (__bf16)(acc[fm][fn][r] + bcol[fn]);
                    *(bf16x4*)(vp + ((size_t)(bb * 512 + nb + fn * 16 + lq)) * 512
                               + l0 + fm * 16) = pv;
                }
        }
    } else {
        float bcol[4];
#pragma unroll
        for (int fn = 0; fn < 4; ++fn) bcol[fn] = bias0[n0 + CB + fn * 16 + lq];
#pragma unroll
        for (int fm = 0; fm < 4; ++fm)
#pragma unroll
            for (int fn = 0; fn < 4; ++fn) {
                const int n = n0 + CB + fn * 16 + lq;
#pragma unroll
                for (int r = 0; r < 4; ++r) {
                    const int m = m0 + RB + fm * 16 + lg * 4 + r;
                    float v = acc[fm][fn][r] + bcol[fn];
                    if constexpr (EPI == 1) {
                        __hip_bfloat16* Co = (__hip_bfloat16*)out0;
                        const size_t idx = (size_t)m * Ndim + n;
                        Co[idx] = __float2bfloat16((float)Res[idx] + v);
                    } else {  // EPI == 2: tanh-GELU
                        ((__hip_bfloat16*)out0)[(size_t)m * Ndim + n] =
                            __float2bfloat16(gelu_tanh(v));
                    }
                }
            }
    }
}

// ---------------------------------------------------------------------------
// Flash attention, paired q-chunks (qcA, 7-qcA share staged K/V tiles).
// Grid (B*H, 4) = 1024 blocks, 40 KiB LDS -> 4 blocks/CU.
// T13 defer-max: skip O-rescale when max growth <= 8 (wave-uniform, __all).
// ---------------------------------------------------------------------------
__global__ __launch_bounds__(256, 4) void attn_kernel(
    const __hip_bfloat16* __restrict__ Q, const __hip_bfloat16* __restrict__ K,
    const __hip_bfloat16* __restrict__ VT, __hip_bfloat16* __restrict__ Out,
    const int* __restrict__ case_ids, const __hip_bfloat16* __restrict__ tab,
    int layer)
{
    __shared__ __align__(16) __bf16 Ks[2][64 * 64];
    __shared__ __align__(16) __bf16 Vs[2][64 * 64];
    __shared__ __align__(16) __bf16 Pl[4][16 * 64];

    const int bh = blockIdx.x;
    const int b = bh >> 3, hh = bh & 7;
    const int qcA = blockIdx.y;
    const int qcB = 7 - qcA;
    const int t = threadIdx.x;
    const int w = t >> 6, lane = t & 63;
    const int lq = lane & 15, lg = lane >> 4;
    const int swz = lq & 7;

    const int rA = w * 16 + (lane >> 3);
    const int swsrc = ((lane & 7) ^ (lane >> 3)) << 4;
    const __hip_bfloat16* kg0 = K  + ((size_t)b * L_ + rA) * D_ + hh * HD_;
    const __hip_bfloat16* vg0 = VT + ((size_t)b * D_ + hh * HD_ + rA) * L_;

    auto stage = [&](int buf, int kv0) {
        const char* gk = (const char*)(kg0 + (size_t)kv0 * D_) + swsrc;
        GLD16(gk,                      (char*)Ks[buf] + w * 2048);
        GLD16(gk + (size_t)8 * D_ * 2, (char*)Ks[buf] + w * 2048 + 1024);
        const char* gv = (const char*)(vg0 + kv0) + swsrc;
        GLD16(gv,                      (char*)Vs[buf] + w * 2048);
        GLD16(gv + (size_t)8 * L_ * 2, (char*)Vs[buf] + w * 2048 + 1024);
    };

    stage(0, 0);

    const int qloc = w * 16 + lq;
    const int qrowA = qcA * 64 + qloc;
    const int qrowB = qcB * 64 + qloc;
    const size_t tbase = (((size_t)layer * B_ + b) * H_ + hh) * C_;
    const __hip_bfloat16* ciqA = tab + (tbase + case_ids[b * L_ + qrowA]) * L_;
    const __hip_bfloat16* ciqB = tab + (tbase + case_ids[b * L_ + qrowB]) * L_;

    const __hip_bfloat16* qpA = Q + ((size_t)b * L_ + qrowA) * D_ + hh * HD_;
    const __hip_bfloat16* qpB = Q + ((size_t)b * L_ + qrowB) * D_ + hh * HD_;
    const bf16x8 qfA0 = *(const bf16x8*)(qpA + lg * 8);
    const bf16x8 qfA1 = *(const bf16x8*)(qpA + 32 + lg * 8);
    const bf16x8 qfB0 = *(const bf16x8*)(qpB + lg * 8);
    const bf16x8 qfB1 = *(const bf16x8*)(qpB + 32 + lg * 8);

    float mA = -1e30f, lA = 0.f, mB = -1e30f, lB = 0.f;
    f32x4 oA[4] = {}, oB[4] = {};
    int cur = 0;

    auto process = [&](const bf16x8 qf0, const bf16x8 qf1,
                       const __hip_bfloat16* ciq, int qcX,
                       float& m_run, float& l_run, f32x4* o,
                       const char* kb, const char* vb2, int kt) {
        bf16x4 bb[4];
#pragma unroll
        for (int c = 0; c < 4; ++c)
            bb[c] = *(const bf16x4*)(ciq + kt * 64 + 16 * c + lg * 4);

        f32x4 s[4] = {};
        __builtin_amdgcn_s_setprio(1);
#pragma unroll
        for (int c = 0; c < 4; ++c) {
            const bf16x8 ka = *(const bf16x8*)(kb + (16 * c + lq) * 128 + ((lg ^ swz) << 4));
            s[c] = MFMA16(ka, qf0, s[c]);
            const bf16x8 kc = *(const bf16x8*)(kb + (16 * c + lq) * 128 + (((4 + lg) ^ swz) << 4));
            s[c] = MFMA16(kc, qf1, s[c]);
        }
        __builtin_amdgcn_s_setprio(0);

        const bool dtile = (kt == qcX);
        float xs[16];
#pragma unroll
        for (int c = 0; c < 4; ++c)
#pragma unroll
            for (int r = 0; r < 4; ++r) {
                const int kvl = 16 * c + lg * 4 + r;
                float v = s[c][r] * 0.125f + (float)bb[c][r];
                xs[4 * c + r] = (dtile && (kvl > qloc)) ? -1e9f : v;
            }

        float a0 = fmaxf(fmaxf(xs[0], xs[1]),  fmaxf(xs[2], xs[3]));
        float a1 = fmaxf(fmaxf(xs[4], xs[5]),  fmaxf(xs[6], xs[7]));
        float a2 = fmaxf(fmaxf(xs[8], xs[9]),  fmaxf(xs[10], xs[11]));
        float a3 = fmaxf(fmaxf(xs[12], xs[13]), fmaxf(xs[14], xs[15]));
        float pmax = fmaxf(fmaxf(a0, a1), fmaxf(a2, a3));
        pmax = fmaxf(pmax, __shfl_xor(pmax, 16, 64));
        pmax = fmaxf(pmax, __shfl_xor(pmax, 32, 64));

        // T13 defer-max: rescale only if some q-row's max grew by > 8.
        if (!__all(pmax - m_run <= 8.f)) {
            const float mnew = fmaxf(m_run, pmax);
            const float corr = __expf(m_run - mnew);
            m_run = mnew;
            l_run *= corr;
            float cr[4];
#pragma unroll
            for (int r = 0; r < 4; ++r) cr[r] = __shfl(corr, lg * 4 + r, 64);
#pragma unroll
            for (int nt = 0; nt < 4; ++nt)
#pragma unroll
                for (int r = 0; r < 4; ++r) o[nt][r] *= cr[r];
        }

        float ps = 0.f;
#pragma unroll
        for (int j = 0; j < 16; ++j) { xs[j] = __expf(xs[j] - m_run); ps += xs[j]; }
        ps += __shfl_xor(ps, 16, 64);
        ps += __shfl_xor(ps, 32, 64);
        l_run += ps;

        char* pw = (char*)Pl[w];
#pragma unroll
        for (int c = 0; c < 4; ++c) {
            bf16x4 pv;
#pragma unroll
            for (int r = 0; r < 4; ++r) pv[r] = (__bf16)xs[4 * c + r];
            const int slot = (2 * c + (lg >> 1)) ^ swz;
            *(bf16x4*)(pw + lq * 128 + (slot << 4) + ((lg & 1) << 3)) = pv;
        }

        __builtin_amdgcn_s_setprio(1);
#pragma unroll
        for (int hf = 0; hf < 2; ++hf) {
            const bf16x8 pf = *(const bf16x8*)(pw + lq * 128 + (((hf * 4 + lg) ^ swz) << 4));
#pragma unroll
            for (int nt = 0; nt < 4; ++nt) {
                const bf16x8 vf = *(const bf16x8*)(vb2 + (nt * 16 + lq) * 128
                                                   + (((hf * 4 + lg) ^ swz) << 4));
                o[nt] = MFMA16(pf, vf, o[nt]);
            }
        }
        __builtin_amdgcn_s_setprio(0);
    };

    for (int kt = 0; kt <= qcB; ++kt) {
        if (kt) __builtin_amdgcn_s_barrier();
        if (kt < qcB) {
            stage(cur ^ 1, (kt + 1) * 64);
            asm volatile("s_waitcnt vmcnt(4)" ::: "memory");
        } else {
            asm volatile("s_waitcnt vmcnt(0)" ::: "memory");
        }
        __builtin_amdgcn_s_barrier();
        __builtin_amdgcn_sched_barrier(0);

        const char* kb  = (const char*)Ks[cur];
        const char* vb2 = (const char*)Vs[cur];

        process(qfB0, qfB1, ciqB, qcB, mB, lB, oB, kb, vb2, kt);
        if (kt <= qcA)
            process(qfA0, qfA1, ciqA, qcA, mA, lA, oA, kb, vb2, kt);
        cur ^= 1;
    }

    auto writeout = [&](float l_run, f32x4* o, int qcX) {
        const float inv = 1.f / l_run;
        float ir[4];
#pragma unroll
        for (int r = 0; r < 4; ++r) ir[r] = __shfl(inv, lg * 4 + r, 64);
        __hip_bfloat16* op = Out + ((size_t)b * L_ + qcX * 64 + w * 16) * D_ + hh * HD_;
#pragma unroll
        for (int nt = 0; nt < 4; ++nt)
#pragma unroll
            for (int r = 0; r < 4; ++r)
                op[(size_t)(lg * 4 + r) * D_ + nt * 16 + lq] =
                    __float2bfloat16(o[nt][r] * ir[r]);
    };
    writeout(lA, oA, qcA);
    writeout(lB, oB, qcB);
}

// ---------------------------------------------------------------------------
extern "C" void kernel_launch(void* const* d_in, const int* in_sizes, int n_in,
                              void* d_out, int out_size, void* d_ws, size_t ws_size,
                              hipStream_t stream)
{
    const float* x_in  = (const float*)d_in[0];
    const int*   cids  = (const int*)  d_in[1];
    const int*   amask = (const int*)  d_in[2];
    const float* Wq = (const float*)d_in[3];
    const float* bq = (const float*)d_in[4];
    const float* Wk = (const float*)d_in[5];
    const float* bk = (const float*)d_in[6];
    const float* Wv = (const float*)d_in[7];
    const float* bv = (const float*)d_in[8];
    const float* Wo = (const float*)d_in[9];
    const float* bo = (const float*)d_in[10];
    const float* ln1g = (const float*)d_in[11];
    const float* ln1b = (const float*)d_in[12];
    const float* ln2g = (const float*)d_in[13];
    const float* ln2b = (const float*)d_in[14];
    const float* W1 = (const float*)d_in[15];
    const float* b1 = (const float*)d_in[16];
    const float* W2 = (const float*)d_in[17];
    const float* b2 = (const float*)d_in[18];
    const float* cbias = (const float*)d_in[19];
    const float* vbias = (const float*)d_in[20];
    const float* fng = (const float*)d_in[21];
    const float* fnb = (const float*)d_in[22];

    char* w = (char*)d_ws;
    __hip_bfloat16* x_ws = (__hip_bfloat16*)w;  w += (size_t)MTOK * D_ * 2;
    __hip_bfloat16* hbuf = (__hip_bfloat16*)w;  w += (size_t)MTOK * D_ * 2;
    __hip_bfloat16* qbuf = (__hip_bfloat16*)w;  w += (size_t)MTOK * D_ * 2;
    __hip_bfloat16* kbuf = (__hip_bfloat16*)w;  w += (size_t)MTOK * D_ * 2;
    __hip_bfloat16* vtb  = (__hip_bfloat16*)w;  w += (size_t)MTOK * D_ * 2;
    __hip_bfloat16* ffb  = (__hip_bfloat16*)w;  w += (size_t)MTOK * F_ * 2;
    __hip_bfloat16* WqkvT = (__hip_bfloat16*)w; w += (size_t)NL_ * 3 * D_ * D_ * 2;
    __hip_bfloat16* WoT  = (__hip_bfloat16*)w;  w += (size_t)NL_ * D_ * D_ * 2;
    __hip_bfloat16* W1T  = (__hip_bfloat16*)w;  w += (size_t)NL_ * D_ * F_ * 2;
    __hip_bfloat16* W2T  = (__hip_bfloat16*)w;  w += (size_t)NL_ * D_ * F_ * 2;
    __hip_bfloat16* btab = (__hip_bfloat16*)w;  w += (size_t)NL_ * B_ * H_ * C_ * L_ * 2;

    const size_t qkvZ = (size_t)3 * D_ * D_;
    const dim3 tb(32, 8);
    transpose_w<<<dim3(D_/32, D_/32, NL_), tb, 0, stream>>>(Wq, WqkvT,           D_, D_, qkvZ);
    transpose_w<<<dim3(D_/32, D_/32, NL_), tb, 0, stream>>>(Wk, WqkvT + D_*D_,   D_, D_, qkvZ);
    transpose_w<<<dim3(D_/32, D_/32, NL_), tb, 0, stream>>>(Wv, WqkvT + 2*D_*D_, D_, D_, qkvZ);
    transpose_w<<<dim3(D_/32, D_/32, NL_), tb, 0, stream>>>(Wo, WoT, D_, D_, (size_t)D_*D_);
    transpose_w<<<dim3(F_/32, D_/32, NL_), tb, 0, stream>>>(W1, W1T, D_, F_, (size_t)D_*F_);
    transpose_w<<<dim3(D_/32, F_/32, NL_), tb, 0, stream>>>(W2, W2T, F_, D_, (size_t)D_*F_);

    bias_build<<<(NL_ * B_ * H_ * C_ * L_) / 256, 256, 0, stream>>>(
        cids, amask, cbias, vbias, btab);

    cvt_f32_bf16<<<4096, 256, 0, stream>>>((const float4*)x_in, x_ws,
                                           MTOK * D_ / 8);

    const dim3 gQKV(12, 128);  // WM=2: 1536 blocks = 2 rounds at 3/CU
    const dim3 gO(4, 128);     // 512 blocks
    const dim3 gW1(16, 64);    // WM=4: 1024 blocks = 2 rounds at 2/CU
    const dim3 gW2(4, 128);    // 512 blocks

    for (int i = 0; i < NL_; ++i) {
        ln_kernel<__hip_bfloat16><<<MTOK/4, 256, 0, stream>>>(
            x_ws, ln1g + i * D_, ln1b + i * D_, hbuf);

        gemm_r5<4, 2><<<gQKV, 256, 0, stream>>>(hbuf, WqkvT + (size_t)i * qkvZ,
            bq + i*D_, bk + i*D_, bv + i*D_, qbuf, kbuf, vtb, nullptr, 512, D_);

        attn_kernel<<<dim3(B_ * H_, 4), 256, 0, stream>>>(
            qbuf, kbuf, vtb, hbuf, cids, btab, i);

        gemm_r5<1, 2><<<gO, 256, 0, stream>>>(hbuf, WoT + (size_t)i*D_*D_,
            bo + i*D_, nullptr, nullptr, x_ws, nullptr, nullptr, x_ws, D_, D_);

        ln_kernel<__hip_bfloat16><<<MTOK/4, 256, 0, stream>>>(
            x_ws, ln2g + i * D_, ln2b + i * D_, hbuf);

        gemm_r5<2, 4><<<gW1, 512, 0, stream>>>(hbuf, W1T + (size_t)i*D_*F_,
            b1 + i*F_, nullptr, nullptr, ffb, nullptr, nullptr, nullptr, F_, D_);

        gemm_r5<1, 2><<<gW2, 256, 0, stream>>>(ffb, W2T + (size_t)i*D_*F_,
            b2 + i*D_, nullptr, nullptr, x_ws, nullptr, nullptr, x_ws, D_, F_);
    }

    ln_kernel<float><<<MTOK/4, 256, 0, stream>>>(x_ws, fng, fnb, (float*)d_out);
}